// Round 8
// baseline (318.250 us; speedup 1.0000x reference)
//
#include <hip/hip_runtime.h>

// Problem constants
#define BB 16
#define NL 256
#define RR 24
#define LL 32
#define NN (NL*NL)        // 65536
#define BNN (BB*NN)       // 1048576
#define TT 64             // FW tile
#define NBLK 4            // 256/64

// Output layout (float32), reference return order.
#define O_TDT 0
#define O_RT  16
#define O_TAT 32
#define O_TD  96
#define O_UNS 112
#define O_TTR 128
#define O_TT  144
#define O_ND  1048720

// LDS: flat 64x64 arrays, XOR-swizzled at float4 granularity. Logical (row,
// chunk) -> physical chunk = chunk ^ (row&15). Stride stays 64 (64 KB total,
// the proven size) while A-column b128 reads hit 16 distinct bank-quads.
#define IDX4(r, ch) (((r)<<6) + ((((ch) ^ ((r)&15)))<<2))
#define LD4(A, r, ch) (*(float4*)&A[IDX4((r),(ch))])

static __device__ __forceinline__ void atomicMinF(float* a, float v){
    atomicMin((unsigned int*)a, __float_as_uint(v));  // ok for non-negative floats
}

static __device__ __forceinline__ void fix4(float dv[4], float hv[4], int gi, int gj0){
    #pragma unroll
    for (int e = 0; e < 4; e++){
        int gj = gj0 + e;
        hv[e] = (gi != gj && dv[e] < 1e37f) ? 1.f : 0.f;
        if (gi == gj) dv[e] = 0.f;
    }
}

// ---------------- init: dist = INF (float4), accumulators = 0 ----------------
__global__ __launch_bounds__(1024) void k_init(float4* __restrict__ dist4, float* __restrict__ acc){
    int idx = blockIdx.x*1024 + threadIdx.x;
    float inf = __builtin_huge_valf();
    dist4[idx] = make_float4(inf, inf, inf, inf);
    if (blockIdx.x == 0 && threadIdx.x < 256) acc[threadIdx.x] = 0.f;
}

// ---------------- route edges: one wave per (b,r) ----------------
__global__ void k_routes(const float* __restrict__ dtm, const int* __restrict__ routes,
                         float* __restrict__ dist, float* __restrict__ acc){
    int br = blockIdx.x; int b = br / RR, r = br % RR;
    int lane = threadIdx.x;
    __shared__ int   s[LL];
    __shared__ float lf[LL], lr[LL], cf[LL], cr[LL];
    if (lane < LL) s[lane] = routes[(b*RR + r)*LL + lane];
    __syncthreads();
    if (lane < LL-1){
        int a0 = s[lane], a1 = s[lane+1];
        const float* dt = dtm + b*NN;
        lf[lane] = dt[a0*NL + a1] + 60.0f;   // MEAN_STOP_TIME_S
        lr[lane] = dt[a1*NL + a0] + 60.0f;
    }
    __syncthreads();
    if (lane == 0){
        float af = 0.f, ar = 0.f;
        cf[0] = 0.f; cr[0] = 0.f;
        for (int l = 0; l < LL-1; l++){
            af += lf[l]; ar += lr[l];
            cf[l+1] = af; cr[l+1] = ar;
        }
        atomicAdd(&acc[b*16 + 1], af + ar);  // total_route_time
    }
    __syncthreads();
    for (int p = lane; p < LL*LL; p += 64){
        int i = p >> 5, j = p & 31;
        if (j > i){
            atomicMinF(&dist[b*NN + s[i]*NL + s[j]], cf[j] - cf[i]); // fwd
            atomicMinF(&dist[b*NN + s[j]*NL + s[i]], cr[j] - cr[i]); // rev
        }
    }
}

// ---------------- one full FW round in a single dispatch -----------------------
// dst(ti,tj) = min(D0, C0 (x) K* (x) B0); 256 blocks x 256 thr; 4x4/thread,
// k-blocked x4, all-b128 swizzled LDS. Double-buffered src/dst.
__global__ __launch_bounds__(256) void k_fw_round(
        const float* __restrict__ srcD, const float* __restrict__ srcH,
        float* __restrict__ dstD, float* __restrict__ dstH, int kb, int dofix){
    int b  = blockIdx.y;
    int m  = blockIdx.x;
    int ti = m >> 2, tj = m & 3;
    int t  = threadIdx.x;
    int r0  = (t >> 4) * 4;        // 4 owned rows
    int cch = t & 15;              // owned col chunk (cols cch*4..cch*4+3)
    int c04 = cch * 4;
    __shared__ float KD[4096], KH[4096];   // K -> K*; later C0
    __shared__ float BD[4096], BH[4096];   // B0; later M = K* (x) B0
    const float* Kg  = srcD + b*NN + kb*TT*(NL+1);
    const float* KgH = srcH + b*NN + kb*TT*(NL+1);
    const float* Bg  = srcD + b*NN + kb*TT*NL + tj*TT;
    const float* BgH = srcH + b*NN + kb*TT*NL + tj*TT;
    const float* Cg  = srcD + b*NN + ti*TT*NL + kb*TT;
    const float* CgH = srcH + b*NN + ti*TT*NL + kb*TT;
    const float* Dg  = srcD + b*NN + ti*TT*NL + tj*TT;
    const float* DgH = srcH + b*NN + ti*TT*NL + tj*TT;

    // ---- stage K and B0 into LDS (4 float4 per thread per matrix) ----
    #pragma unroll
    for (int u = 0; u < 4; u++){
        int fid = u*256 + t;             // 0..1023
        int row = fid >> 4, ch = fid & 15, c4 = ch*4;
        float4 v = *(const float4*)(Kg + row*NL + c4);
        float kd[4] = {v.x,v.y,v.z,v.w}, kh[4];
        float4 w = *(const float4*)(Bg + row*NL + c4);
        float bd[4] = {w.x,w.y,w.z,w.w}, bh[4];
        if (dofix){
            fix4(kd, kh, kb*TT+row, kb*TT+c4);
            fix4(bd, bh, kb*TT+row, tj*TT+c4);
        } else {
            float4 q = *(const float4*)(KgH + row*NL + c4);
            kh[0]=q.x; kh[1]=q.y; kh[2]=q.z; kh[3]=q.w;
            float4 r2 = *(const float4*)(BgH + row*NL + c4);
            bh[0]=r2.x; bh[1]=r2.y; bh[2]=r2.z; bh[3]=r2.w;
        }
        LD4(KD,row,ch) = make_float4(kd[0],kd[1],kd[2],kd[3]);
        LD4(KH,row,ch) = make_float4(kh[0],kh[1],kh[2],kh[3]);
        LD4(BD,row,ch) = make_float4(bd[0],bd[1],bd[2],bd[3]);
        LD4(BH,row,ch) = make_float4(bh[0],bh[1],bh[2],bh[3]);
    }
    __syncthreads();

    // ---- in-LDS hierarchical closure of K (sub-tile 16, 4 sub-rounds) ----
    for (int skb = 0; skb < 4; skb++){
        int s0 = skb*16, sch = skb*4;
        // p1': wave 0 closes 16x16 diag sub-tile via shfl (no barriers)
        if (t < 64){
            int i = t >> 2, jg = t & 3;
            int base = IDX4(s0+i, sch+jg);
            float md[4], mh[4];
            #pragma unroll
            for (int c = 0; c < 4; c++){ md[c] = KD[base+c]; mh[c] = KH[base+c]; }
            #pragma unroll
            for (int k = 0; k < 16; k++){
                float rd[4], rh[4];
                #pragma unroll
                for (int c = 0; c < 4; c++){
                    rd[c] = __shfl(md[c], (k<<2)|jg);
                    rh[c] = __shfl(mh[c], (k<<2)|jg);
                }
                float cd = __shfl(md[k&3], (i<<2)|(k>>2));
                float ch = __shfl(mh[k&3], (i<<2)|(k>>2));
                #pragma unroll
                for (int c = 0; c < 4; c++){
                    float alt = cd + rd[c];
                    if (alt < md[c]){ md[c] = alt; mh[c] = ch + rh[c]; }
                }
            }
            #pragma unroll
            for (int c = 0; c < 4; c++){ KD[base+c] = md[c]; KH[base+c] = mh[c]; }
        }
        __syncthreads();
        // p2': row strip (16 band rows x 64 cols) + col strip (64 rows x 16
        // band cols); 4 elements of each per thread, b128 B-reads.
        int rsr = s0 + (t >> 4);            // row-strip row
        int csr = t >> 2;                   // col-strip row
        int csc = sch + (t & 3);            // col-strip chunk
        float rsd[4], rsh[4], csd[4], csh[4];
        {
            float4 v = LD4(KD, rsr, cch), w = LD4(KH, rsr, cch);
            rsd[0]=v.x; rsd[1]=v.y; rsd[2]=v.z; rsd[3]=v.w;
            rsh[0]=w.x; rsh[1]=w.y; rsh[2]=w.z; rsh[3]=w.w;
            float4 v2 = LD4(KD, csr, csc), w2 = LD4(KH, csr, csc);
            csd[0]=v2.x; csd[1]=v2.y; csd[2]=v2.z; csd[3]=v2.w;
            csh[0]=w2.x; csh[1]=w2.y; csh[2]=w2.z; csh[3]=w2.w;
        }
        #pragma unroll
        for (int k = 0; k < 16; k++){
            int kch = sch + (k>>2), ko = k & 3;
            float ad = KD[IDX4(rsr,kch)+ko], ah = KH[IDX4(rsr,kch)+ko];
            float4 bv = LD4(KD, s0+k, cch), bq = LD4(KH, s0+k, cch);
            float bd[4]={bv.x,bv.y,bv.z,bv.w}, bh[4]={bq.x,bq.y,bq.z,bq.w};
            #pragma unroll
            for (int e = 0; e < 4; e++){
                float alt = ad + bd[e];
                if (alt < rsd[e]){ rsd[e] = alt; rsh[e] = ah + bh[e]; }
            }
            float a2 = KD[IDX4(csr,kch)+ko], a2h = KH[IDX4(csr,kch)+ko];
            float4 b2 = LD4(KD, s0+k, csc), b2q = LD4(KH, s0+k, csc);
            float b2d[4]={b2.x,b2.y,b2.z,b2.w}, b2h[4]={b2q.x,b2q.y,b2q.z,b2q.w};
            #pragma unroll
            for (int e = 0; e < 4; e++){
                float alt = a2 + b2d[e];
                if (alt < csd[e]){ csd[e] = alt; csh[e] = a2h + b2h[e]; }
            }
        }
        __syncthreads();   // all p2' reads done
        LD4(KD, rsr, cch) = make_float4(rsd[0],rsd[1],rsd[2],rsd[3]);
        LD4(KH, rsr, cch) = make_float4(rsh[0],rsh[1],rsh[2],rsh[3]);
        LD4(KD, csr, csc) = make_float4(csd[0],csd[1],csd[2],csd[3]);
        LD4(KH, csr, csc) = make_float4(csh[0],csh[1],csh[2],csh[3]);
        __syncthreads();
        // p3': full 64x64, 4x4 per thread, k-blocked x4, barrier-free k loop
        float dd[4][4], hh[4][4];
        #pragma unroll
        for (int i = 0; i < 4; i++){
            float4 v = LD4(KD, r0+i, cch), w = LD4(KH, r0+i, cch);
            dd[i][0]=v.x; dd[i][1]=v.y; dd[i][2]=v.z; dd[i][3]=v.w;
            hh[i][0]=w.x; hh[i][1]=w.y; hh[i][2]=w.z; hh[i][3]=w.w;
        }
        #pragma unroll
        for (int q4 = 0; q4 < 4; q4++){
            int kch = sch + q4, kr = s0 + q4*4;
            float a[4][4], ah[4][4], bm[4][4], bh[4][4];
            #pragma unroll
            for (int i = 0; i < 4; i++){
                float4 av = LD4(KD, r0+i, kch), aq = LD4(KH, r0+i, kch);
                a[i][0]=av.x; a[i][1]=av.y; a[i][2]=av.z; a[i][3]=av.w;
                ah[i][0]=aq.x; ah[i][1]=aq.y; ah[i][2]=aq.z; ah[i][3]=aq.w;
            }
            #pragma unroll
            for (int q = 0; q < 4; q++){
                float4 bv = LD4(KD, kr+q, cch), bq = LD4(KH, kr+q, cch);
                bm[q][0]=bv.x; bm[q][1]=bv.y; bm[q][2]=bv.z; bm[q][3]=bv.w;
                bh[q][0]=bq.x; bh[q][1]=bq.y; bh[q][2]=bq.z; bh[q][3]=bq.w;
            }
            #pragma unroll
            for (int q = 0; q < 4; q++)
            #pragma unroll
            for (int i = 0; i < 4; i++)
            #pragma unroll
            for (int j = 0; j < 4; j++){
                float alt = a[i][q] + bm[q][j];
                if (alt < dd[i][j]){ dd[i][j] = alt; hh[i][j] = ah[i][q] + bh[q][j]; }
            }
        }
        __syncthreads();   // all p3' reads done
        #pragma unroll
        for (int i = 0; i < 4; i++){
            LD4(KD, r0+i, cch) = make_float4(dd[i][0],dd[i][1],dd[i][2],dd[i][3]);
            LD4(KH, r0+i, cch) = make_float4(hh[i][0],hh[i][1],hh[i][2],hh[i][3]);
        }
        __syncthreads();
    }

    // ---- M = K* (x) B0 (K* 0-diag -> includes identity), 4x4, k-blocked ----
    float inf = __builtin_huge_valf();
    float md[4][4], mh[4][4];
    #pragma unroll
    for (int i = 0; i < 4; i++)
    #pragma unroll
    for (int j = 0; j < 4; j++){ md[i][j] = inf; mh[i][j] = 0.f; }
    #pragma unroll 2
    for (int q4 = 0; q4 < 16; q4++){
        int kr = q4*4;
        float a[4][4], ah[4][4], bm[4][4], bh[4][4];
        #pragma unroll
        for (int i = 0; i < 4; i++){
            float4 av = LD4(KD, r0+i, q4), aq = LD4(KH, r0+i, q4);
            a[i][0]=av.x; a[i][1]=av.y; a[i][2]=av.z; a[i][3]=av.w;
            ah[i][0]=aq.x; ah[i][1]=aq.y; ah[i][2]=aq.z; ah[i][3]=aq.w;
        }
        #pragma unroll
        for (int q = 0; q < 4; q++){
            float4 bv = LD4(BD, kr+q, cch), bq = LD4(BH, kr+q, cch);
            bm[q][0]=bv.x; bm[q][1]=bv.y; bm[q][2]=bv.z; bm[q][3]=bv.w;
            bh[q][0]=bq.x; bh[q][1]=bq.y; bh[q][2]=bq.z; bh[q][3]=bq.w;
        }
        #pragma unroll
        for (int q = 0; q < 4; q++)
        #pragma unroll
        for (int i = 0; i < 4; i++)
        #pragma unroll
        for (int j = 0; j < 4; j++){
            float alt = a[i][q] + bm[q][j];
            if (alt < md[i][j]){ md[i][j] = alt; mh[i][j] = ah[i][q] + bh[q][j]; }
        }
    }
    __syncthreads();   // all K*/B0 reads done
    // write M over B0; load C0 from (immutable) src over K*
    #pragma unroll
    for (int i = 0; i < 4; i++){
        LD4(BD, r0+i, cch) = make_float4(md[i][0],md[i][1],md[i][2],md[i][3]);
        LD4(BH, r0+i, cch) = make_float4(mh[i][0],mh[i][1],mh[i][2],mh[i][3]);
        float4 cv = *(const float4*)(Cg + (r0+i)*NL + c04);
        float cd[4] = {cv.x,cv.y,cv.z,cv.w}, chv[4];
        if (dofix){
            fix4(cd, chv, ti*TT+r0+i, kb*TT+c04);
        } else {
            float4 cq = *(const float4*)(CgH + (r0+i)*NL + c04);
            chv[0]=cq.x; chv[1]=cq.y; chv[2]=cq.z; chv[3]=cq.w;
        }
        LD4(KD, r0+i, cch) = make_float4(cd[0],cd[1],cd[2],cd[3]);
        LD4(KH, r0+i, cch) = make_float4(chv[0],chv[1],chv[2],chv[3]);
    }
    __syncthreads();

    // ---- dst = min(D0, C0 (x) M) ----
    float dd[4][4], hh[4][4];
    #pragma unroll
    for (int i = 0; i < 4; i++){
        float4 v = *(const float4*)(Dg + (r0+i)*NL + c04);
        float dv[4] = {v.x,v.y,v.z,v.w}, hv[4];
        if (dofix){
            fix4(dv, hv, ti*TT+r0+i, tj*TT+c04);
        } else {
            float4 w = *(const float4*)(DgH + (r0+i)*NL + c04);
            hv[0]=w.x; hv[1]=w.y; hv[2]=w.z; hv[3]=w.w;
        }
        #pragma unroll
        for (int e = 0; e < 4; e++){ dd[i][e] = dv[e]; hh[i][e] = hv[e]; }
    }
    #pragma unroll 2
    for (int q4 = 0; q4 < 16; q4++){
        int kr = q4*4;
        float a[4][4], ah[4][4], bm[4][4], bh[4][4];
        #pragma unroll
        for (int i = 0; i < 4; i++){
            float4 av = LD4(KD, r0+i, q4), aq = LD4(KH, r0+i, q4);
            a[i][0]=av.x; a[i][1]=av.y; a[i][2]=av.z; a[i][3]=av.w;
            ah[i][0]=aq.x; ah[i][1]=aq.y; ah[i][2]=aq.z; ah[i][3]=aq.w;
        }
        #pragma unroll
        for (int q = 0; q < 4; q++){
            float4 bv = LD4(BD, kr+q, cch), bq = LD4(BH, kr+q, cch);
            bm[q][0]=bv.x; bm[q][1]=bv.y; bm[q][2]=bv.z; bm[q][3]=bv.w;
            bh[q][0]=bq.x; bh[q][1]=bq.y; bh[q][2]=bq.z; bh[q][3]=bq.w;
        }
        #pragma unroll
        for (int q = 0; q < 4; q++)
        #pragma unroll
        for (int i = 0; i < 4; i++)
        #pragma unroll
        for (int j = 0; j < 4; j++){
            float alt = a[i][q] + bm[q][j];
            if (alt < dd[i][j]){ dd[i][j] = alt; hh[i][j] = ah[i][q] + bh[q][j]; }
        }
    }
    float* Od = dstD + b*NN + ti*TT*NL + tj*TT;
    float* Oh = dstH + b*NN + ti*TT*NL + tj*TT;
    #pragma unroll
    for (int i = 0; i < 4; i++){
        *(float4*)(Od + (r0+i)*NL + c04) = make_float4(dd[i][0],dd[i][1],dd[i][2],dd[i][3]);
        *(float4*)(Oh + (r0+i)*NL + c04) = make_float4(hh[i][0],hh[i][1],hh[i][2],hh[i][3]);
    }
}

// ---------------- epilogue: trip_times + reductions + fused finalize ----------
__global__ __launch_bounds__(1024) void k_epi(const float4* __restrict__ dist4,
        const float4* __restrict__ hops4, const float4* __restrict__ demand4,
        float* __restrict__ out, float* __restrict__ acc){
    int b = blockIdx.y;
    int fid = (b*NN >> 2) + blockIdx.x*1024 + threadIdx.x;   // float4 index
    float4 dv = dist4[fid], hv = hops4[fid], mv = demand4[fid];
    float ds[4] = {dv.x,dv.y,dv.z,dv.w};
    float hs[4] = {hv.x,hv.y,hv.z,hv.w};
    float ms[4] = {mv.x,mv.y,mv.z,mv.w};
    float s0=0,s1=0,s2=0,s3=0,s4=0,s5=0,s6=0,s7=0,s8=0;
    float tts[4];
    #pragma unroll
    for (int e = 0; e < 4; e++){
        float d = ds[e], h = hs[e], dm = ms[e];
        bool np = !(d < 1e37f);
        float pl = np ? 0.f : h + 1.f;
        float tr = (pl == 0.f) ? 0.f : pl - 2.f;
        float tt = np ? 0.f : d + tr*300.f;   // AVG_TRANSFER_WAIT_TIME_S
        tts[e] = tt;
        s0 += dm*tt;
        s1 += dm*tr;
        s2 += np ? dm : 0.f;
        s3 += dm;
        s4 += (np && dm > 0.f) ? 1.f : 0.f;
        s5 += (tr == 0.f) ? dm : 0.f;
        s6 += (tr == 1.f) ? dm : 0.f;
        s7 += (tr == 2.f) ? dm : 0.f;
        s8 += (tr > 2.f) ? dm : 0.f;
    }
    ((float4*)(out + O_TT))[fid] = make_float4(tts[0],tts[1],tts[2],tts[3]);
    #define RED(x) { x += __shfl_down(x,32); x += __shfl_down(x,16); x += __shfl_down(x,8); \
                     x += __shfl_down(x,4);  x += __shfl_down(x,2);  x += __shfl_down(x,1); }
    RED(s0) RED(s1) RED(s2) RED(s3) RED(s4) RED(s5) RED(s6) RED(s7) RED(s8)
    __shared__ float red[16][9];
    int w = threadIdx.x >> 6;
    if ((threadIdx.x & 63) == 0){
        red[w][0]=s0; red[w][1]=s1; red[w][2]=s2; red[w][3]=s3; red[w][4]=s4;
        red[w][5]=s5; red[w][6]=s6; red[w][7]=s7; red[w][8]=s8;
    }
    __syncthreads();
    if (threadIdx.x < 9){
        float v = 0.f;
        #pragma unroll
        for (int ww = 0; ww < 16; ww++) v += red[ww][threadIdx.x];
        // acc slots: 0 tdt, 1 rt, 2 ttrans, 3 uns, 4 tdem, 5 ndis, 6 b0, 7 b1, 8 b2, 9 bun
        int slot = (threadIdx.x == 0) ? 0 : threadIdx.x + 1;
        atomicAdd(&acc[b*16 + slot], v);
    }
    __syncthreads();
    __shared__ int isLast;
    if (threadIdx.x == 0){
        unsigned prev = atomicAdd((unsigned int*)(acc + 255), 1u);
        isLast = (prev == 255u) ? 1 : 0;   // 16x16 = 256 blocks
    }
    __syncthreads();
    if (isLast && threadIdx.x < BB){
        int bb = threadIdx.x;
        float a[10];
        #pragma unroll
        for (int s = 0; s < 10; s++) a[s] = atomicAdd(&acc[bb*16 + s], 0.f);  // coherent read
        out[O_TDT + bb] = a[0];
        out[O_RT  + bb] = a[1];
        out[O_TAT + 4*bb + 0] = a[6];
        out[O_TAT + 4*bb + 1] = a[7];
        out[O_TAT + 4*bb + 2] = a[8];
        out[O_TAT + 4*bb + 3] = a[9] + a[3];
        out[O_TD  + bb] = a[4];
        out[O_UNS + bb] = a[3];
        out[O_TTR + bb] = a[2];
        out[O_ND  + bb] = a[5];
    }
}

extern "C" void kernel_launch(void* const* d_in, const int* in_sizes, int n_in,
                              void* d_out, int out_size, void* d_ws, size_t ws_size,
                              hipStream_t stream){
    (void)in_sizes; (void)n_in; (void)out_size; (void)ws_size;
    const float* dtm    = (const float*)d_in[0];
    const float* demand = (const float*)d_in[1];
    const int*   routes = (const int*)d_in[2];
    float* out   = (float*)d_out;
    float* distA = (float*)d_ws;            // buf0 D
    float* hopsA = distA + BNN;             // buf0 H
    float* distB = hopsA + BNN;             // buf1 D
    float* hopsB = distB + BNN;             // buf1 H
    float* acc   = hopsB + BNN;             // 256 floats (incl. counter at [255])

    k_init  <<<BNN/4096, 1024, 0, stream>>>((float4*)distA, acc);
    k_routes<<<BB*RR,      64, 0, stream>>>(dtm, routes, distA, acc);
    // 4 rounds, double-buffered: 0: A->B, 1: B->A, 2: A->B, 3: B->A (ends in A)
    k_fw_round<<<dim3(16,BB), 256, 0, stream>>>(distA, hopsA, distB, hopsB, 0, 1);
    k_fw_round<<<dim3(16,BB), 256, 0, stream>>>(distB, hopsB, distA, hopsA, 1, 0);
    k_fw_round<<<dim3(16,BB), 256, 0, stream>>>(distA, hopsA, distB, hopsB, 2, 0);
    k_fw_round<<<dim3(16,BB), 256, 0, stream>>>(distB, hopsB, distA, hopsA, 3, 0);
    k_epi<<<dim3(16,BB), 1024, 0, stream>>>((const float4*)distA, (const float4*)hopsA,
                                            (const float4*)demand, out, acc);
}

// Round 9
// 285.858 us; speedup vs baseline: 1.1133x; 1.1133x over previous
//
#include <hip/hip_runtime.h>

// Problem constants
#define BB 16
#define NL 256
#define RR 24
#define LL 32
#define NN (NL*NL)        // 65536
#define BNN (BB*NN)       // 1048576
#define TT 64             // FW tile
#define NBLK 4            // 256/64

// Output layout (float32), reference return order.
#define O_TDT 0
#define O_RT  16
#define O_TAT 32
#define O_TD  96
#define O_UNS 112
#define O_TTR 128
#define O_TT  144
#define O_ND  1048720

// LDS: flat 64x64 arrays, XOR-swizzled at float4 granularity (round-8 proven:
// conflicts 6.97M -> 254K). Logical (row,chunk) -> physical chunk ^ (row&15).
#define IDX4(r, ch) (((r)<<6) + ((((ch) ^ ((r)&15)))<<2))
#define LD4(A, r, ch) (*(float4*)&A[IDX4((r),(ch))])

static __device__ __forceinline__ void atomicMinF(float* a, float v){
    atomicMin((unsigned int*)a, __float_as_uint(v));  // ok for non-negative floats
}

static __device__ __forceinline__ void fix4(float dv[4], float hv[4], int gi, int gj0){
    #pragma unroll
    for (int e = 0; e < 4; e++){
        int gj = gj0 + e;
        hv[e] = (gi != gj && dv[e] < 1e37f) ? 1.f : 0.f;
        if (gi == gj) dv[e] = 0.f;
    }
}

// ---------------- init: dist = INF (float4), accumulators = 0 ----------------
__global__ __launch_bounds__(1024) void k_init(float4* __restrict__ dist4, float* __restrict__ acc){
    int idx = blockIdx.x*1024 + threadIdx.x;
    float inf = __builtin_huge_valf();
    dist4[idx] = make_float4(inf, inf, inf, inf);
    if (blockIdx.x == 0 && threadIdx.x < 256) acc[threadIdx.x] = 0.f;
}

// ---------------- route edges: one wave per (b,r) ----------------
__global__ void k_routes(const float* __restrict__ dtm, const int* __restrict__ routes,
                         float* __restrict__ dist, float* __restrict__ acc){
    int br = blockIdx.x; int b = br / RR, r = br % RR;
    int lane = threadIdx.x;
    __shared__ int   s[LL];
    __shared__ float lf[LL], lr[LL], cf[LL], cr[LL];
    if (lane < LL) s[lane] = routes[(b*RR + r)*LL + lane];
    __syncthreads();
    if (lane < LL-1){
        int a0 = s[lane], a1 = s[lane+1];
        const float* dt = dtm + b*NN;
        lf[lane] = dt[a0*NL + a1] + 60.0f;   // MEAN_STOP_TIME_S
        lr[lane] = dt[a1*NL + a0] + 60.0f;
    }
    __syncthreads();
    if (lane == 0){
        float af = 0.f, ar = 0.f;
        cf[0] = 0.f; cr[0] = 0.f;
        for (int l = 0; l < LL-1; l++){
            af += lf[l]; ar += lr[l];
            cf[l+1] = af; cr[l+1] = ar;
        }
        atomicAdd(&acc[b*16 + 1], af + ar);  // total_route_time
    }
    __syncthreads();
    for (int p = lane; p < LL*LL; p += 64){
        int i = p >> 5, j = p & 31;
        if (j > i){
            atomicMinF(&dist[b*NN + s[i]*NL + s[j]], cf[j] - cf[i]); // fwd
            atomicMinF(&dist[b*NN + s[j]*NL + s[i]], cr[j] - cr[i]); // rev
        }
    }
}

// ---------------- one full FW round in a single dispatch -----------------------
// dst(ti,tj) = min(D0, C0 (x) K* (x) B0); 256 blocks x 512 thr (8 waves/CU);
// 2x4/thread, k-blocked b128 swizzled LDS. Double-buffered src/dst.
__global__ __launch_bounds__(512) void k_fw_round(
        const float* __restrict__ srcD, const float* __restrict__ srcH,
        float* __restrict__ dstD, float* __restrict__ dstH, int kb, int dofix){
    int b  = blockIdx.y;
    int m  = blockIdx.x;
    int ti = m >> 2, tj = m & 3;
    int t  = threadIdx.x;
    int rp  = (t >> 4) * 2;        // 2 owned rows: rp, rp+1
    int cch = t & 15;              // owned col chunk
    int c04 = cch * 4;
    __shared__ float KD[4096], KH[4096];   // K -> K*; later C0
    __shared__ float BD[4096], BH[4096];   // B0; later M = K* (x) B0
    const float* Kg  = srcD + b*NN + kb*TT*(NL+1);
    const float* KgH = srcH + b*NN + kb*TT*(NL+1);
    const float* Bg  = srcD + b*NN + kb*TT*NL + tj*TT;
    const float* BgH = srcH + b*NN + kb*TT*NL + tj*TT;
    const float* Cg  = srcD + b*NN + ti*TT*NL + kb*TT;
    const float* CgH = srcH + b*NN + ti*TT*NL + kb*TT;
    const float* Dg  = srcD + b*NN + ti*TT*NL + tj*TT;
    const float* DgH = srcH + b*NN + ti*TT*NL + tj*TT;

    // ---- stage K and B0 into LDS (2 float4 per thread per matrix) ----
    #pragma unroll
    for (int u = 0; u < 2; u++){
        int fid = u*512 + t;             // 0..1023
        int row = fid >> 4, ch = fid & 15, c4 = ch*4;
        float4 v = *(const float4*)(Kg + row*NL + c4);
        float kd[4] = {v.x,v.y,v.z,v.w}, kh[4];
        float4 w = *(const float4*)(Bg + row*NL + c4);
        float bd[4] = {w.x,w.y,w.z,w.w}, bh[4];
        if (dofix){
            fix4(kd, kh, kb*TT+row, kb*TT+c4);
            fix4(bd, bh, kb*TT+row, tj*TT+c4);
        } else {
            float4 q = *(const float4*)(KgH + row*NL + c4);
            kh[0]=q.x; kh[1]=q.y; kh[2]=q.z; kh[3]=q.w;
            float4 r2 = *(const float4*)(BgH + row*NL + c4);
            bh[0]=r2.x; bh[1]=r2.y; bh[2]=r2.z; bh[3]=r2.w;
        }
        LD4(KD,row,ch) = make_float4(kd[0],kd[1],kd[2],kd[3]);
        LD4(KH,row,ch) = make_float4(kh[0],kh[1],kh[2],kh[3]);
        LD4(BD,row,ch) = make_float4(bd[0],bd[1],bd[2],bd[3]);
        LD4(BH,row,ch) = make_float4(bh[0],bh[1],bh[2],bh[3]);
    }
    __syncthreads();

    // ---- in-LDS hierarchical closure of K (sub-tile 16, 4 sub-rounds) ----
    for (int skb = 0; skb < 4; skb++){
        int s0 = skb*16, sch = skb*4;
        // p1': wave 0 closes 16x16 diag sub-tile via shfl (no barriers)
        if (t < 64){
            int i = t >> 2, jg = t & 3;
            int base = IDX4(s0+i, sch+jg);
            float md[4], mh[4];
            #pragma unroll
            for (int c = 0; c < 4; c++){ md[c] = KD[base+c]; mh[c] = KH[base+c]; }
            #pragma unroll
            for (int k = 0; k < 16; k++){
                float rd[4], rh[4];
                #pragma unroll
                for (int c = 0; c < 4; c++){
                    rd[c] = __shfl(md[c], (k<<2)|jg);
                    rh[c] = __shfl(mh[c], (k<<2)|jg);
                }
                float cd = __shfl(md[k&3], (i<<2)|(k>>2));
                float ch = __shfl(mh[k&3], (i<<2)|(k>>2));
                #pragma unroll
                for (int c = 0; c < 4; c++){
                    float alt = cd + rd[c];
                    if (alt < md[c]){ md[c] = alt; mh[c] = ch + rh[c]; }
                }
            }
            #pragma unroll
            for (int c = 0; c < 4; c++){ KD[base+c] = md[c]; KH[base+c] = mh[c]; }
        }
        __syncthreads();
        // p2': threads 0..255 do the row strip (16 band rows x 64 cols, one
        // float4 each); threads 256..511 do the col strip (64 rows x 16 band
        // cols, one float4 each). Band-square double-write is a benign
        // same-value race (identical inputs/formula). Uniform barriers.
        float sd[4], sh[4];
        int wrow, wch;
        if (t < 256){
            int rsr = s0 + (t >> 4);
            wrow = rsr; wch = t & 15;
            float4 v = LD4(KD, rsr, wch), w = LD4(KH, rsr, wch);
            sd[0]=v.x; sd[1]=v.y; sd[2]=v.z; sd[3]=v.w;
            sh[0]=w.x; sh[1]=w.y; sh[2]=w.z; sh[3]=w.w;
            #pragma unroll
            for (int k = 0; k < 16; k++){
                int kch = sch + (k>>2), ko = k & 3;
                float ad = KD[IDX4(rsr,kch)+ko], ah = KH[IDX4(rsr,kch)+ko];
                float4 bv = LD4(KD, s0+k, wch), bq = LD4(KH, s0+k, wch);
                float bd[4]={bv.x,bv.y,bv.z,bv.w}, bh[4]={bq.x,bq.y,bq.z,bq.w};
                #pragma unroll
                for (int e = 0; e < 4; e++){
                    float alt = ad + bd[e];
                    if (alt < sd[e]){ sd[e] = alt; sh[e] = ah + bh[e]; }
                }
            }
        } else {
            int t2 = t - 256;
            int csr = t2 >> 2;
            wrow = csr; wch = sch + (t2 & 3);
            float4 v = LD4(KD, csr, wch), w = LD4(KH, csr, wch);
            sd[0]=v.x; sd[1]=v.y; sd[2]=v.z; sd[3]=v.w;
            sh[0]=w.x; sh[1]=w.y; sh[2]=w.z; sh[3]=w.w;
            #pragma unroll
            for (int k = 0; k < 16; k++){
                int kch = sch + (k>>2), ko = k & 3;
                float a2 = KD[IDX4(csr,kch)+ko], a2h = KH[IDX4(csr,kch)+ko];
                float4 bv = LD4(KD, s0+k, wch), bq = LD4(KH, s0+k, wch);
                float bd[4]={bv.x,bv.y,bv.z,bv.w}, bh[4]={bq.x,bq.y,bq.z,bq.w};
                #pragma unroll
                for (int e = 0; e < 4; e++){
                    float alt = a2 + bd[e];
                    if (alt < sd[e]){ sd[e] = alt; sh[e] = a2h + bh[e]; }
                }
            }
        }
        __syncthreads();   // all p2' reads done
        LD4(KD, wrow, wch) = make_float4(sd[0],sd[1],sd[2],sd[3]);
        LD4(KH, wrow, wch) = make_float4(sh[0],sh[1],sh[2],sh[3]);
        __syncthreads();
        // p3': full 64x64, 2x4 per thread, k-blocked x4, barrier-free k loop
        float dd[2][4], hh[2][4];
        #pragma unroll
        for (int i = 0; i < 2; i++){
            float4 v = LD4(KD, rp+i, cch), w = LD4(KH, rp+i, cch);
            dd[i][0]=v.x; dd[i][1]=v.y; dd[i][2]=v.z; dd[i][3]=v.w;
            hh[i][0]=w.x; hh[i][1]=w.y; hh[i][2]=w.z; hh[i][3]=w.w;
        }
        #pragma unroll
        for (int q4 = 0; q4 < 4; q4++){
            int kch = sch + q4, kr = s0 + q4*4;
            float a[2][4], ah[2][4], bm[4][4], bh[4][4];
            #pragma unroll
            for (int i = 0; i < 2; i++){
                float4 av = LD4(KD, rp+i, kch), aq = LD4(KH, rp+i, kch);
                a[i][0]=av.x; a[i][1]=av.y; a[i][2]=av.z; a[i][3]=av.w;
                ah[i][0]=aq.x; ah[i][1]=aq.y; ah[i][2]=aq.z; ah[i][3]=aq.w;
            }
            #pragma unroll
            for (int q = 0; q < 4; q++){
                float4 bv = LD4(KD, kr+q, cch), bq = LD4(KH, kr+q, cch);
                bm[q][0]=bv.x; bm[q][1]=bv.y; bm[q][2]=bv.z; bm[q][3]=bv.w;
                bh[q][0]=bq.x; bh[q][1]=bq.y; bh[q][2]=bq.z; bh[q][3]=bq.w;
            }
            #pragma unroll
            for (int q = 0; q < 4; q++)
            #pragma unroll
            for (int i = 0; i < 2; i++)
            #pragma unroll
            for (int j = 0; j < 4; j++){
                float alt = a[i][q] + bm[q][j];
                if (alt < dd[i][j]){ dd[i][j] = alt; hh[i][j] = ah[i][q] + bh[q][j]; }
            }
        }
        __syncthreads();   // all p3' reads done
        #pragma unroll
        for (int i = 0; i < 2; i++){
            LD4(KD, rp+i, cch) = make_float4(dd[i][0],dd[i][1],dd[i][2],dd[i][3]);
            LD4(KH, rp+i, cch) = make_float4(hh[i][0],hh[i][1],hh[i][2],hh[i][3]);
        }
        __syncthreads();
    }

    // ---- M = K* (x) B0 (K* 0-diag -> includes identity), 2x4, k-blocked ----
    float inf = __builtin_huge_valf();
    float md[2][4], mh[2][4];
    #pragma unroll
    for (int i = 0; i < 2; i++)
    #pragma unroll
    for (int j = 0; j < 4; j++){ md[i][j] = inf; mh[i][j] = 0.f; }
    #pragma unroll 4
    for (int q4 = 0; q4 < 16; q4++){
        int kr = q4*4;
        float a[2][4], ah[2][4], bm[4][4], bh[4][4];
        #pragma unroll
        for (int i = 0; i < 2; i++){
            float4 av = LD4(KD, rp+i, q4), aq = LD4(KH, rp+i, q4);
            a[i][0]=av.x; a[i][1]=av.y; a[i][2]=av.z; a[i][3]=av.w;
            ah[i][0]=aq.x; ah[i][1]=aq.y; ah[i][2]=aq.z; ah[i][3]=aq.w;
        }
        #pragma unroll
        for (int q = 0; q < 4; q++){
            float4 bv = LD4(BD, kr+q, cch), bq = LD4(BH, kr+q, cch);
            bm[q][0]=bv.x; bm[q][1]=bv.y; bm[q][2]=bv.z; bm[q][3]=bv.w;
            bh[q][0]=bq.x; bh[q][1]=bq.y; bh[q][2]=bq.z; bh[q][3]=bq.w;
        }
        #pragma unroll
        for (int q = 0; q < 4; q++)
        #pragma unroll
        for (int i = 0; i < 2; i++)
        #pragma unroll
        for (int j = 0; j < 4; j++){
            float alt = a[i][q] + bm[q][j];
            if (alt < md[i][j]){ md[i][j] = alt; mh[i][j] = ah[i][q] + bh[q][j]; }
        }
    }
    __syncthreads();   // all K*/B0 reads done
    // write M over B0; load C0 from (immutable) src over K*
    #pragma unroll
    for (int i = 0; i < 2; i++){
        LD4(BD, rp+i, cch) = make_float4(md[i][0],md[i][1],md[i][2],md[i][3]);
        LD4(BH, rp+i, cch) = make_float4(mh[i][0],mh[i][1],mh[i][2],mh[i][3]);
        float4 cv = *(const float4*)(Cg + (rp+i)*NL + c04);
        float cd[4] = {cv.x,cv.y,cv.z,cv.w}, chv[4];
        if (dofix){
            fix4(cd, chv, ti*TT+rp+i, kb*TT+c04);
        } else {
            float4 cq = *(const float4*)(CgH + (rp+i)*NL + c04);
            chv[0]=cq.x; chv[1]=cq.y; chv[2]=cq.z; chv[3]=cq.w;
        }
        LD4(KD, rp+i, cch) = make_float4(cd[0],cd[1],cd[2],cd[3]);
        LD4(KH, rp+i, cch) = make_float4(chv[0],chv[1],chv[2],chv[3]);
    }
    __syncthreads();

    // ---- dst = min(D0, C0 (x) M) ----
    float dd[2][4], hh[2][4];
    #pragma unroll
    for (int i = 0; i < 2; i++){
        float4 v = *(const float4*)(Dg + (rp+i)*NL + c04);
        float dv[4] = {v.x,v.y,v.z,v.w}, hv[4];
        if (dofix){
            fix4(dv, hv, ti*TT+rp+i, tj*TT+c04);
        } else {
            float4 w = *(const float4*)(DgH + (rp+i)*NL + c04);
            hv[0]=w.x; hv[1]=w.y; hv[2]=w.z; hv[3]=w.w;
        }
        #pragma unroll
        for (int e = 0; e < 4; e++){ dd[i][e] = dv[e]; hh[i][e] = hv[e]; }
    }
    #pragma unroll 4
    for (int q4 = 0; q4 < 16; q4++){
        int kr = q4*4;
        float a[2][4], ah[2][4], bm[4][4], bh[4][4];
        #pragma unroll
        for (int i = 0; i < 2; i++){
            float4 av = LD4(KD, rp+i, q4), aq = LD4(KH, rp+i, q4);
            a[i][0]=av.x; a[i][1]=av.y; a[i][2]=av.z; a[i][3]=av.w;
            ah[i][0]=aq.x; ah[i][1]=aq.y; ah[i][2]=aq.z; ah[i][3]=aq.w;
        }
        #pragma unroll
        for (int q = 0; q < 4; q++){
            float4 bv = LD4(BD, kr+q, cch), bq = LD4(BH, kr+q, cch);
            bm[q][0]=bv.x; bm[q][1]=bv.y; bm[q][2]=bv.z; bm[q][3]=bv.w;
            bh[q][0]=bq.x; bh[q][1]=bq.y; bh[q][2]=bq.z; bh[q][3]=bq.w;
        }
        #pragma unroll
        for (int q = 0; q < 4; q++)
        #pragma unroll
        for (int i = 0; i < 2; i++)
        #pragma unroll
        for (int j = 0; j < 4; j++){
            float alt = a[i][q] + bm[q][j];
            if (alt < dd[i][j]){ dd[i][j] = alt; hh[i][j] = ah[i][q] + bh[q][j]; }
        }
    }
    float* Od = dstD + b*NN + ti*TT*NL + tj*TT;
    float* Oh = dstH + b*NN + ti*TT*NL + tj*TT;
    #pragma unroll
    for (int i = 0; i < 2; i++){
        *(float4*)(Od + (rp+i)*NL + c04) = make_float4(dd[i][0],dd[i][1],dd[i][2],dd[i][3]);
        *(float4*)(Oh + (rp+i)*NL + c04) = make_float4(hh[i][0],hh[i][1],hh[i][2],hh[i][3]);
    }
}

// ---------------- epilogue: trip_times + reductions + fused finalize ----------
__global__ __launch_bounds__(1024) void k_epi(const float4* __restrict__ dist4,
        const float4* __restrict__ hops4, const float4* __restrict__ demand4,
        float* __restrict__ out, float* __restrict__ acc){
    int b = blockIdx.y;
    int fid = (b*NN >> 2) + blockIdx.x*1024 + threadIdx.x;   // float4 index
    float4 dv = dist4[fid], hv = hops4[fid], mv = demand4[fid];
    float ds[4] = {dv.x,dv.y,dv.z,dv.w};
    float hs[4] = {hv.x,hv.y,hv.z,hv.w};
    float ms[4] = {mv.x,mv.y,mv.z,mv.w};
    float s0=0,s1=0,s2=0,s3=0,s4=0,s5=0,s6=0,s7=0,s8=0;
    float tts[4];
    #pragma unroll
    for (int e = 0; e < 4; e++){
        float d = ds[e], h = hs[e], dm = ms[e];
        bool np = !(d < 1e37f);
        float pl = np ? 0.f : h + 1.f;
        float tr = (pl == 0.f) ? 0.f : pl - 2.f;
        float tt = np ? 0.f : d + tr*300.f;   // AVG_TRANSFER_WAIT_TIME_S
        tts[e] = tt;
        s0 += dm*tt;
        s1 += dm*tr;
        s2 += np ? dm : 0.f;
        s3 += dm;
        s4 += (np && dm > 0.f) ? 1.f : 0.f;
        s5 += (tr == 0.f) ? dm : 0.f;
        s6 += (tr == 1.f) ? dm : 0.f;
        s7 += (tr == 2.f) ? dm : 0.f;
        s8 += (tr > 2.f) ? dm : 0.f;
    }
    ((float4*)(out + O_TT))[fid] = make_float4(tts[0],tts[1],tts[2],tts[3]);
    #define RED(x) { x += __shfl_down(x,32); x += __shfl_down(x,16); x += __shfl_down(x,8); \
                     x += __shfl_down(x,4);  x += __shfl_down(x,2);  x += __shfl_down(x,1); }
    RED(s0) RED(s1) RED(s2) RED(s3) RED(s4) RED(s5) RED(s6) RED(s7) RED(s8)
    __shared__ float red[16][9];
    int w = threadIdx.x >> 6;
    if ((threadIdx.x & 63) == 0){
        red[w][0]=s0; red[w][1]=s1; red[w][2]=s2; red[w][3]=s3; red[w][4]=s4;
        red[w][5]=s5; red[w][6]=s6; red[w][7]=s7; red[w][8]=s8;
    }
    __syncthreads();
    if (threadIdx.x < 9){
        float v = 0.f;
        #pragma unroll
        for (int ww = 0; ww < 16; ww++) v += red[ww][threadIdx.x];
        // acc slots: 0 tdt, 1 rt, 2 ttrans, 3 uns, 4 tdem, 5 ndis, 6 b0, 7 b1, 8 b2, 9 bun
        int slot = (threadIdx.x == 0) ? 0 : threadIdx.x + 1;
        atomicAdd(&acc[b*16 + slot], v);
    }
    __syncthreads();
    __shared__ int isLast;
    if (threadIdx.x == 0){
        unsigned prev = atomicAdd((unsigned int*)(acc + 255), 1u);
        isLast = (prev == 255u) ? 1 : 0;   // 16x16 = 256 blocks
    }
    __syncthreads();
    if (isLast && threadIdx.x < BB){
        int bb = threadIdx.x;
        float a[10];
        #pragma unroll
        for (int s = 0; s < 10; s++) a[s] = atomicAdd(&acc[bb*16 + s], 0.f);  // coherent read
        out[O_TDT + bb] = a[0];
        out[O_RT  + bb] = a[1];
        out[O_TAT + 4*bb + 0] = a[6];
        out[O_TAT + 4*bb + 1] = a[7];
        out[O_TAT + 4*bb + 2] = a[8];
        out[O_TAT + 4*bb + 3] = a[9] + a[3];
        out[O_TD  + bb] = a[4];
        out[O_UNS + bb] = a[3];
        out[O_TTR + bb] = a[2];
        out[O_ND  + bb] = a[5];
    }
}

extern "C" void kernel_launch(void* const* d_in, const int* in_sizes, int n_in,
                              void* d_out, int out_size, void* d_ws, size_t ws_size,
                              hipStream_t stream){
    (void)in_sizes; (void)n_in; (void)out_size; (void)ws_size;
    const float* dtm    = (const float*)d_in[0];
    const float* demand = (const float*)d_in[1];
    const int*   routes = (const int*)d_in[2];
    float* out   = (float*)d_out;
    float* distA = (float*)d_ws;            // buf0 D
    float* hopsA = distA + BNN;             // buf0 H
    float* distB = hopsA + BNN;             // buf1 D
    float* hopsB = distB + BNN;             // buf1 H
    float* acc   = hopsB + BNN;             // 256 floats (incl. counter at [255])

    k_init  <<<BNN/4096, 1024, 0, stream>>>((float4*)distA, acc);
    k_routes<<<BB*RR,      64, 0, stream>>>(dtm, routes, distA, acc);
    // 4 rounds, double-buffered: 0: A->B, 1: B->A, 2: A->B, 3: B->A (ends in A)
    k_fw_round<<<dim3(16,BB), 512, 0, stream>>>(distA, hopsA, distB, hopsB, 0, 1);
    k_fw_round<<<dim3(16,BB), 512, 0, stream>>>(distB, hopsB, distA, hopsA, 1, 0);
    k_fw_round<<<dim3(16,BB), 512, 0, stream>>>(distA, hopsA, distB, hopsB, 2, 0);
    k_fw_round<<<dim3(16,BB), 512, 0, stream>>>(distB, hopsB, distA, hopsA, 3, 0);
    k_epi<<<dim3(16,BB), 1024, 0, stream>>>((const float4*)distA, (const float4*)hopsA,
                                            (const float4*)demand, out, acc);
}